// Round 1
// baseline (911.744 us; speedup 1.0000x reference)
//
#include <hip/hip_runtime.h>

#define T_LEN 2048
#define B_SZ  64
#define I_DIM 128
#define H_DIM 256

typedef _Float16 f16;
typedef _Float16 f16x8 __attribute__((ext_vector_type(8)));
typedef float    f32x4 __attribute__((ext_vector_type(4)));

__device__ __forceinline__ float fast_sigmoid(float z) {
  return __builtin_amdgcn_rcpf(1.0f + __expf(-z));
}

// Raw barrier: orders LDS (lgkmcnt(0)) but leaves global prefetch loads in
// flight across the barrier (no vmcnt drain, unlike __syncthreads).
#define WG_BARRIER() do {                                  \
  asm volatile("s_waitcnt lgkmcnt(0)" ::: "memory");       \
  __builtin_amdgcn_s_barrier();                            \
  asm volatile("" ::: "memory");                           \
  __builtin_amdgcn_sched_barrier(0);                       \
} while (0)

// ---------------------------------------------------------------------------
// Kernel 1: xproj[t][b][:] = x[b][t][:] @ Wx + bias   (written into d_out)
// grid (16, 64): blockIdx.x = 128-t chunk, blockIdx.y = b. 256 thr = 4 waves.
// Wave w owns cols [64w, 64w+64).
// ---------------------------------------------------------------------------
__global__ __launch_bounds__(256) void xproj_kernel(
    const float* __restrict__ x, const float* __restrict__ W,
    const float* __restrict__ bias, float* __restrict__ out) {
  const int b    = blockIdx.y;
  const int tc   = blockIdx.x * 128;
  const int w    = threadIdx.x >> 6;
  const int lane = threadIdx.x & 63;
  const int cl   = lane & 15;
  const int kh   = lane >> 4;

  // Wx fragments: B[k][c], c = 64w+16g+cl, k = 32q+8kh+j (8 consecutive k/lane)
  f16x8 Bf[4][4];
#pragma unroll
  for (int g = 0; g < 4; ++g) {
    const int c = 64 * w + 16 * g + cl;
#pragma unroll
    for (int q = 0; q < 4; ++q)
#pragma unroll
      for (int j = 0; j < 8; ++j)
        Bf[g][q][j] = (f16)W[(32 * q + 8 * kh + j) * H_DIM + c];
  }
  float bv[4];
#pragma unroll
  for (int g = 0; g < 4; ++g) bv[g] = bias[64 * w + 16 * g + cl];

#pragma unroll 1
  for (int tb = 0; tb < 128; tb += 16) {
    const int t0 = tc + tb;
    // A fragments: A[r][k] = x[b][t0+r][k], r = cl, k = 8kh+j+32q
    const float* xrow = x + ((size_t)b * T_LEN + (t0 + cl)) * I_DIM + 8 * kh;
    f16x8 Af[4];
#pragma unroll
    for (int q = 0; q < 4; ++q) {
      float4 u0 = *(const float4*)(xrow + 32 * q);
      float4 u1 = *(const float4*)(xrow + 32 * q + 4);
      f16x8 a;
      a[0] = (f16)u0.x; a[1] = (f16)u0.y; a[2] = (f16)u0.z; a[3] = (f16)u0.w;
      a[4] = (f16)u1.x; a[5] = (f16)u1.y; a[6] = (f16)u1.z; a[7] = (f16)u1.w;
      Af[q] = a;
    }
#pragma unroll
    for (int g = 0; g < 4; ++g) {
      f32x4 acc = {0.f, 0.f, 0.f, 0.f};
#pragma unroll
      for (int q = 0; q < 4; ++q)
        acc = __builtin_amdgcn_mfma_f32_16x16x32_f16(Af[q], Bf[g][q], acc, 0, 0, 0);
      // D: row = 4kh+j, col = cl (+16g+64w)
#pragma unroll
      for (int j = 0; j < 4; ++j) {
        const int t = t0 + 4 * kh + j;
        out[((size_t)t * B_SZ + b) * H_DIM + 64 * w + 16 * g + cl] = acc[j] + bv[g];
      }
    }
  }
}

// ---------------------------------------------------------------------------
// Kernel 2: sequential scan. One workgroup per batch row b. 512 thr = 8 waves,
// wave w owns output cols [32w, 32w+32) with Wh fragments VGPR-resident.
// h is exchanged between waves via a 2x512B double-buffered LDS row; only the
// 4 lanes with (lane&15)==0 re-read A fragments each step (M-tile rows 1..15
// are hard zero). xp is read in-place from d_out (kernel 1's output) with a
// 4-step-deep register prefetch, and h_t overwrites the same row afterwards.
// ---------------------------------------------------------------------------
#define RNN_STEP(tt, pp, RB) do {                                            \
  if (cl == 0) {                                                             \
    _Pragma("unroll")                                                        \
    for (int q = 0; q < 8; ++q)                                              \
      Af[q] = *(const f16x8*)&hbuf[RB][32 * q + 8 * kh];                     \
  }                                                                          \
  f32x4 a0 = {0.f, 0.f, 0.f, 0.f};                                           \
  f32x4 a1 = {0.f, 0.f, 0.f, 0.f};                                           \
  _Pragma("unroll")                                                          \
  for (int q = 0; q < 8; ++q) {                                              \
    a0 = __builtin_amdgcn_mfma_f32_16x16x32_f16(Af[q], Bf[0][q], a0, 0, 0, 0); \
    a1 = __builtin_amdgcn_mfma_f32_16x16x32_f16(Af[q], Bf[1][q], a1, 0, 0, 0); \
  }                                                                          \
  float zs = __shfl(a1[0], (lane - 16) & 63);                                \
  float zz = ((lane < 16) ? a0[0] : zs) + (pp);                              \
  float hh = fast_sigmoid(zz);                                               \
  if (act) {                                                                 \
    op[(size_t)(tt) * rowstride] = hh;                                       \
    hbuf[(RB) ^ 1][colx] = (f16)hh;                                          \
  }                                                                          \
  WG_BARRIER();                                                              \
} while (0)

__global__ __launch_bounds__(512) void rnn_kernel(
    const float* __restrict__ W, float* out) {
  const int b    = blockIdx.x;
  const int w    = threadIdx.x >> 6;
  const int lane = threadIdx.x & 63;
  const int cl   = lane & 15;
  const int kh   = lane >> 4;

  __shared__ __align__(16) f16 hbuf[2][H_DIM];
  if (threadIdx.x < H_DIM) {
    hbuf[0][threadIdx.x] = (f16)0.f;
    hbuf[1][threadIdx.x] = (f16)0.f;
  }

  // Wh fragments (persistent in VGPRs): B[k][c], c = 32w+16g+cl, k = 32q+8kh+j
  f16x8 Bf[2][8];
#pragma unroll
  for (int g = 0; g < 2; ++g) {
    const int c = 32 * w + 16 * g + cl;
#pragma unroll
    for (int q = 0; q < 8; ++q)
#pragma unroll
      for (int j = 0; j < 8; ++j)
        Bf[g][q][j] = (f16)W[(I_DIM + 32 * q + 8 * kh + j) * H_DIM + c];
  }

  // A fragments: rows 1..15 stay zero forever (only 4 lanes/wave load row 0)
  f16x8 Af[8];
#pragma unroll
  for (int q = 0; q < 8; ++q)
#pragma unroll
    for (int j = 0; j < 8; ++j) Af[q][j] = (f16)0.f;

  const bool   act  = (lane < 32);
  const int    colx = 32 * w + (lane & 31);
  const size_t rowstride = (size_t)B_SZ * H_DIM;
  float* op = out + (size_t)b * H_DIM + colx;   // &out[(t*B + b)*H + colx] at t=0

  __syncthreads();

  // xp prefetch pipeline, depth 4
  float p0 = act ? op[0 * rowstride] : 0.f;
  float p1 = act ? op[1 * rowstride] : 0.f;
  float p2 = act ? op[2 * rowstride] : 0.f;
  float p3 = act ? op[3 * rowstride] : 0.f;

#pragma unroll 1
  for (int t = 0; t < T_LEN; t += 4) {
    float n0 = act ? op[(size_t)((t + 4 < T_LEN) ? t + 4 : T_LEN - 1) * rowstride] : 0.f;
    RNN_STEP(t + 0, p0, 0); p0 = n0;
    float n1 = act ? op[(size_t)((t + 5 < T_LEN) ? t + 5 : T_LEN - 1) * rowstride] : 0.f;
    RNN_STEP(t + 1, p1, 1); p1 = n1;
    float n2 = act ? op[(size_t)((t + 6 < T_LEN) ? t + 6 : T_LEN - 1) * rowstride] : 0.f;
    RNN_STEP(t + 2, p2, 0); p2 = n2;
    float n3 = act ? op[(size_t)((t + 7 < T_LEN) ? t + 7 : T_LEN - 1) * rowstride] : 0.f;
    RNN_STEP(t + 3, p3, 1); p3 = n3;
  }
}

extern "C" void kernel_launch(void* const* d_in, const int* in_sizes, int n_in,
                              void* d_out, int out_size, void* d_ws, size_t ws_size,
                              hipStream_t stream) {
  (void)in_sizes; (void)n_in; (void)d_ws; (void)ws_size; (void)out_size;
  const float* x    = (const float*)d_in[0];
  const float* W    = (const float*)d_in[1];
  const float* bias = (const float*)d_in[2];
  float* out = (float*)d_out;

  xproj_kernel<<<dim3(16, 64), 256, 0, stream>>>(x, W, bias, out);
  rnn_kernel<<<64, 512, 0, stream>>>(W, out);
}